// Round 13
// baseline (20.053 us; speedup 1.0000x reference)
//
#include <hip/hip_runtime.h>

#define IW 512
#define IH 512
#define NPIX (IH * IW)
#define NK 6            // steps 1..6 (step 0 is exact identity)
#define GROUPS 8        // group == bid&7 == XCD -> 3 planes per XCD, L2-resident
#define PPT 3
#define LROW 520        // 4 guard + 512 data + 4 guard
#define GOFF 4

typedef float f4v __attribute__((ext_vector_type(4)));

struct RowTap { int rowA; float t0, t1; };

// Row taps for one step (block-uniform). Branch-free remap zeroes weights of
// out-of-range tap rows (vertical zero-pad). The 1/7 mean scale is folded in.
__device__ inline RowTap row_prep(float inv, float yf) {
    const float ysv = fmaf(yf, inv, 256.0f);
    const float fy  = floorf(ysv);
    const float wy  = ysv - fy;
    const int y0 = (int)fy;
    const int yb = min(max(y0, 0), IH - 2);
    const float t0 = (yb == y0 ? 1.0f - wy : 0.0f) + (yb == y0 + 1 ? wy : 0.0f);
    const float t1 = (yb + 1 == y0 ? 1.0f - wy : 0.0f) + (yb + 1 == y0 + 1 ? wy : 0.0f);
    RowTap rt;
    rt.t0 = t0 * (1.0f / 7.0f);   // staged lines carry the /7
    rt.t1 = t1 * (1.0f / 7.0f);
    rt.rowA = yb * IW;
    return rt;
}

// issue 6 row loads + 2 identity loads for plane at base_ into the a-set
#define STAGE_LOAD(base_, idA_, idB_) do {                      \
    const float* __restrict__ _b = (base_);                     \
    a0 = *(const f4v*)(_b + r0.rowA + cq);                      \
    b0 = *(const f4v*)(_b + r0.rowA + IW + cq);                 \
    a1 = *(const f4v*)(_b + r1.rowA + cq);                      \
    b1 = *(const f4v*)(_b + r1.rowA + IW + cq);                 \
    a2 = *(const f4v*)(_b + r2.rowA + cq);                      \
    b2 = *(const f4v*)(_b + r2.rowA + IW + cq);                 \
    idA_ = _b[idoff];                                           \
    idB_ = _b[idoff + 256];                                     \
} while (0)

// row-lerp the arrived a-set and publish into the (single) LDS buffer
#define LERP_WRITE() do {                                       \
    *(f4v*)&rrow[woff]            = r0.t0 * a0 + r0.t1 * b0;    \
    *(f4v*)&rrow[woff + 2 * LROW] = r1.t0 * a1 + r1.t1 * b1;    \
    *(f4v*)&rrow[woff + 4 * LROW] = r2.t0 * a2 + r2.t1 * b2;    \
} while (0)

// horizontal lerp for both owned pixels from LDS, NT store
#define COMPUTE_STORE(cA_, cB_, op_) do {                       \
    float aA = (cA_) * (1.0f / 7.0f);                           \
    float aB = (cB_) * (1.0f / 7.0f);                           \
    _Pragma("unroll")                                           \
    for (int k = 0; k < NK; ++k) {                              \
        const float v0A = rrow[offA[k]];                        \
        const float v1A = rrow[offA[k] + 1];                    \
        const float v0B = rrow[offB[k]];                        \
        const float v1B = rrow[offB[k] + 1];                    \
        aA = fmaf(wxA[k], v1A - v0A, aA + v0A);                 \
        aB = fmaf(wxB[k], v1B - v0B, aB + v0B);                 \
    }                                                           \
    float* _o = (op_);                                          \
    __builtin_nontemporal_store(aA, _o);                        \
    __builtin_nontemporal_store(aB, _o + 256);                  \
} while (0)

__global__ __launch_bounds__(256, 8) void zoomblur_kernel(
    const float* __restrict__ img,
    const float* __restrict__ zoomf,
    float* __restrict__ out)
{
    __shared__ float rrow[NK * LROW];   // 12.5 KB single buffer -> 8 blocks/CU

    const int tid   = threadIdx.x;
    const int bid   = blockIdx.x;
    const int group = bid & (GROUPS - 1);   // == XCD (round-robin dispatch)
    const int y     = bid >> 3;             // one output row per block

    const float zf = 0.85f + 0.30f * zoomf[0];
    const float dz = zf - 1.0f;
    const float yf  = (float)y - 256.0f;
    // split-pixel ownership: x = tid and x = tid+256
    const float xfA = (float)tid - 256.0f;
    const float xfB = (float)tid;

    float invs[NK];
#pragma unroll
    for (int s = 1; s <= NK; ++s)
        invs[s - 1] = __builtin_amdgcn_rcpf(fmaf((float)s * (1.0f / 6.0f), dz, 1.0f));

    // per-thread column taps; guard-zero: clamp into zeroed guard slots,
    // keep plain interior weights (lerp form: one wx per pixel per step)
    int   offA[NK], offB[NK];
    float wxA[NK], wxB[NK];
#pragma unroll
    for (int k = 0; k < NK; ++k) {
        const float inv = invs[k];
        const float xsA = fmaf(xfA, inv, 256.0f);
        const float xsB = fmaf(xfB, inv, 256.0f);
        const float fxA = floorf(xsA);
        const float fxB = floorf(xsB);
        wxA[k] = xsA - fxA;
        wxB[k] = xsB - fxB;
        const int xA = min(max((int)fxA, -2), IW);   // slots 2..516
        const int xB = min(max((int)fxB, -2), IW);
        offA[k] = k * LROW + GOFF + xA;
        offB[k] = k * LROW + GOFF + xB;
    }

    // staging role: thread stages col-quad cq of lines {sbase, sbase+2, sbase+4}
    const int sbase = tid >> 7;             // 0 or 1
    const int cq    = (tid & 127) << 2;     // 0..508
    const RowTap r0 = row_prep(sbase ? invs[1] : invs[0], yf);
    const RowTap r1 = row_prep(sbase ? invs[3] : invs[2], yf);
    const RowTap r2 = row_prep(sbase ? invs[5] : invs[4], yf);
    const int woff = sbase * LROW + GOFF + cq;

    // zero guard slots once (stage writes never touch them)
    if (tid < 48) {
        const int line = tid >> 3;              // 0..5
        const int j    = tid & 7;
        const int slot = (j < 4) ? j : 512 + j; // 0..3, 516..519
        rrow[line * LROW + slot] = 0.0f;
    }

    const int idoff = y * IW + tid;
    const size_t pbase = (size_t)(group * PPT) * NPIX;
    const float* __restrict__ ib = img + pbase;
    float* __restrict__       ob = out + pbase;

    f4v a0, b0, a1, b1, a2, b2;   // in-flight load set (one plane deep)
    float idA0, idB0, idA1, idB1, idA2, idB2;

    // ---- single-buffer pipeline: loads for p+1 are issued before
    //      COMPUTE(p) and consumed after the read-done fence ----
    STAGE_LOAD(ib, idA0, idB0);           // plane 0
    LERP_WRITE();                         // waits plane-0 loads
    __syncthreads();                      // buf ready (plane 0)

    STAGE_LOAD(ib + NPIX, idA1, idB1);    // plane-1 loads fly over compute 0
    COMPUTE_STORE(idA0, idB0, ob + idoff);
    __syncthreads();                      // all reads of buf done
    LERP_WRITE();                         // publish plane 1
    __syncthreads();                      // buf ready (plane 1)

    STAGE_LOAD(ib + 2 * NPIX, idA2, idB2);
    COMPUTE_STORE(idA1, idB1, ob + NPIX + idoff);
    __syncthreads();                      // reads done
    LERP_WRITE();                         // publish plane 2
    __syncthreads();                      // buf ready (plane 2)

    COMPUTE_STORE(idA2, idB2, ob + 2 * NPIX + idoff);
}

extern "C" void kernel_launch(void* const* d_in, const int* in_sizes, int n_in,
                              void* d_out, int out_size, void* d_ws, size_t ws_size,
                              hipStream_t stream) {
    const float* img  = (const float*)d_in[0];
    const float* zoom = (const float*)d_in[1];
    float* out = (float*)d_out;

    dim3 block(256);
    dim3 grid(IH * GROUPS);      // 4096 blocks; bid&7 == XCD, 3 planes each
    zoomblur_kernel<<<grid, block, 0, stream>>>(img, zoom, out);
}